// Round 1
// baseline (617.956 us; speedup 1.0000x reference)
//
#include <hip/hip_runtime.h>

// Problem constants (B=4, L=4096, E=512, H=16, D=32)
#define EMBED  512
#define NHEAD  16
#define HDIM   32
#define NBATCH 4
#define SEQ    4096
#define NROWS  (NBATCH * SEQ)   // 16384
#define FEPS   1e-6f

// ---------------- SGEMM: C[m,n] = sum_k A[m,k] * B[n,k]  (x @ W.T form) ----
// A: M x K row-major, B: N x K row-major, C: M x N row-major.
// EPI: 0 = none, 1 = elu(x)+1, 2 = x * (1/SEQ)
#define BM 128
#define BN 128
#define BKK 16

template <int EPI>
__global__ __launch_bounds__(256, 2)
void gemm_nt(const float* __restrict__ A, const float* __restrict__ B,
             float* __restrict__ C, int M, int N, int K) {
    __shared__ float As[BKK][BM];   // K-outer (transposed) for broadcast reads
    __shared__ float Bs[BKK][BN];

    const int tid = threadIdx.x;
    const int tx  = tid & 15;    // 0..15 -> N direction
    const int ty  = tid >> 4;    // 0..15 -> M direction
    const int bm  = blockIdx.y * BM;
    const int bn  = blockIdx.x * BN;

    // staging: each thread loads 8 floats of A and 8 of B per K-tile
    const int lr = tid >> 1;          // 0..127: row within tile
    const int lc = (tid & 1) << 3;    // 0 or 8: col within K-tile

    const float* Ap = A + (size_t)(bm + lr) * K + lc;
    const float* Bp = B + (size_t)(bn + lr) * K + lc;

    float acc[8][8];
#pragma unroll
    for (int i = 0; i < 8; ++i)
#pragma unroll
        for (int j = 0; j < 8; ++j) acc[i][j] = 0.f;

    for (int k0 = 0; k0 < K; k0 += BKK) {
        float4 a0 = *(const float4*)(Ap + k0);
        float4 a1 = *(const float4*)(Ap + k0 + 4);
        float4 b0 = *(const float4*)(Bp + k0);
        float4 b1 = *(const float4*)(Bp + k0 + 4);
        __syncthreads();   // previous iteration's reads complete
        As[lc + 0][lr] = a0.x; As[lc + 1][lr] = a0.y;
        As[lc + 2][lr] = a0.z; As[lc + 3][lr] = a0.w;
        As[lc + 4][lr] = a1.x; As[lc + 5][lr] = a1.y;
        As[lc + 6][lr] = a1.z; As[lc + 7][lr] = a1.w;
        Bs[lc + 0][lr] = b0.x; Bs[lc + 1][lr] = b0.y;
        Bs[lc + 2][lr] = b0.z; Bs[lc + 3][lr] = b0.w;
        Bs[lc + 4][lr] = b1.x; Bs[lc + 5][lr] = b1.y;
        Bs[lc + 6][lr] = b1.z; Bs[lc + 7][lr] = b1.w;
        __syncthreads();
#pragma unroll
        for (int kk = 0; kk < BKK; ++kk) {
            float af[8], bf[8];
            *(float4*)&af[0] = *(const float4*)&As[kk][ty * 8];
            *(float4*)&af[4] = *(const float4*)&As[kk][ty * 8 + 4];
            *(float4*)&bf[0] = *(const float4*)&Bs[kk][tx * 8];
            *(float4*)&bf[4] = *(const float4*)&Bs[kk][tx * 8 + 4];
#pragma unroll
            for (int i = 0; i < 8; ++i)
#pragma unroll
                for (int j = 0; j < 8; ++j)
                    acc[i][j] = fmaf(af[i], bf[j], acc[i][j]);
        }
    }

#pragma unroll
    for (int i = 0; i < 8; ++i) {
        float o[8];
#pragma unroll
        for (int j = 0; j < 8; ++j) {
            float v = acc[i][j];
            if (EPI == 1) v = (v > 0.f) ? (v + 1.f) : __expf(v);   // elu(x)+1
            else if (EPI == 2) v = v * (1.0f / (float)SEQ);
            o[j] = v;
        }
        float* Cp = C + (size_t)(bm + ty * 8 + i) * N + (bn + tx * 8);
        *(float4*)Cp       = *(float4*)&o[0];
        *(float4*)(Cp + 4) = *(float4*)&o[4];
    }
}

// ---------------- KV[b,h,d,e] = sum_s K[b,s,h,d]*V[b,s,h,e]; Ksum[b,h,d] ----
// grid: (8 s-chunks, 64 bh). fp32 atomics into zeroed buffers.
__global__ __launch_bounds__(256)
void kv_ksum_kernel(const float* __restrict__ Kf, const float* __restrict__ Vf,
                    float* __restrict__ KV, float* __restrict__ Ksum) {
    const int bh = blockIdx.y;           // 0..63
    const int b  = bh >> 4;
    const int h  = bh & 15;
    const int s0 = blockIdx.x * (SEQ / 8);   // 512-row chunk
    const int t  = threadIdx.x;
    const int e  = t & 31;
    const int d0 = (t >> 5) * 4;         // 8 groups of 4 d's

    __shared__ float Ks[8][32];
    __shared__ float Vs[8][32];
    const int r = t >> 5, c = t & 31;

    const float* Kbase = Kf + (size_t)b * SEQ * EMBED + h * HDIM;
    const float* Vbase = Vf + (size_t)b * SEQ * EMBED + h * HDIM;

    float a0 = 0.f, a1 = 0.f, a2 = 0.f, a3 = 0.f, ks = 0.f;
    for (int s = s0; s < s0 + SEQ / 8; s += 8) {
        __syncthreads();
        Ks[r][c] = Kbase[(size_t)(s + r) * EMBED + c];
        Vs[r][c] = Vbase[(size_t)(s + r) * EMBED + c];
        __syncthreads();
#pragma unroll
        for (int rr = 0; rr < 8; ++rr) {
            float v = Vs[rr][e];
            a0 = fmaf(Ks[rr][d0 + 0], v, a0);
            a1 = fmaf(Ks[rr][d0 + 1], v, a1);
            a2 = fmaf(Ks[rr][d0 + 2], v, a2);
            a3 = fmaf(Ks[rr][d0 + 3], v, a3);
        }
        if (t < 32) {
#pragma unroll
            for (int rr = 0; rr < 8; ++rr) ks += Ks[rr][t];
        }
    }
    float* kvp = KV + ((size_t)bh * HDIM + d0) * HDIM + e;
    atomicAdd(kvp + 0 * HDIM, a0);
    atomicAdd(kvp + 1 * HDIM, a1);
    atomicAdd(kvp + 2 * HDIM, a2);
    atomicAdd(kvp + 3 * HDIM, a3);
    if (t < 32) atomicAdd(&Ksum[bh * HDIM + t], ks);
}

// ---------------- message (in-place on Q): Q[l,h,:] <- (L/(Q.Ksum+eps)) * Q@KV[h] --
__global__ __launch_bounds__(512)
void message_kernel(float* __restrict__ Q, const float* __restrict__ KV,
                    const float* __restrict__ Ksum) {
    const int row = blockIdx.x;       // 0..16383
    const int b   = row >> 12;        // row / SEQ
    const int t   = threadIdx.x;
    const int h   = t >> 5, e = t & 31;

    __shared__ float q[EMBED];
    __shared__ float ks[EMBED];
    q[t]  = Q[(size_t)row * EMBED + t];
    ks[t] = Ksum[b * EMBED + t];      // Ksum is [64][32] = b*512 + h*32 + d
    __syncthreads();

    const float* kvh = KV + (size_t)(b * NHEAD + h) * HDIM * HDIM + e;
    float zden = FEPS;
    float m = 0.f;
#pragma unroll
    for (int d = 0; d < HDIM; ++d) {
        float qd = q[h * HDIM + d];
        zden = fmaf(qd, ks[h * HDIM + d], zden);
        m    = fmaf(qd, kvh[d * HDIM], m);
    }
    Q[(size_t)row * EMBED + t] = m * ((float)SEQ / zden);
}

// ---------------- launch ----------------
extern "C" void kernel_launch(void* const* d_in, const int* in_sizes, int n_in,
                              void* d_out, int out_size, void* d_ws, size_t ws_size,
                              hipStream_t stream) {
    const float* query = (const float*)d_in[0];
    const float* key   = (const float*)d_in[1];
    const float* value = (const float*)d_in[2];
    const float* Wq    = (const float*)d_in[3];
    const float* Wk    = (const float*)d_in[4];
    const float* Wv    = (const float*)d_in[5];
    const float* Wm    = (const float*)d_in[6];
    float* out = (float*)d_out;

    float* ws  = (float*)d_ws;
    float* Qb  = ws;                              // 16384*512
    float* Kb  = Qb + (size_t)NROWS * EMBED;      // 16384*512
    float* Vb  = Kb + (size_t)NROWS * EMBED;      // 16384*512
    float* KVb = Vb + (size_t)NROWS * EMBED;      // 64*32*32
    float* KSb = KVb + 64 * HDIM * HDIM;          // 64*32

    // zero the atomic accumulation buffers (ws is poisoned 0xAA each call)
    hipMemsetAsync(KVb, 0, (64 * HDIM * HDIM + 64 * HDIM) * sizeof(float), stream);

    dim3 g(EMBED / BN, NROWS / BM);   // (4, 128) = 512 blocks
    gemm_nt<1><<<g, 256, 0, stream>>>(query, Wq, Qb, NROWS, EMBED, EMBED);
    gemm_nt<1><<<g, 256, 0, stream>>>(key,   Wk, Kb, NROWS, EMBED, EMBED);
    gemm_nt<2><<<g, 256, 0, stream>>>(value, Wv, Vb, NROWS, EMBED, EMBED);

    kv_ksum_kernel<<<dim3(8, 64), 256, 0, stream>>>(Kb, Vb, KVb, KSb);
    message_kernel<<<NROWS, 512, 0, stream>>>(Qb, KVb, KSb);

    gemm_nt<0><<<g, 256, 0, stream>>>(Qb, Wm, out, NROWS, EMBED, EMBED);
}

// Round 2
// 367.571 us; speedup vs baseline: 1.6812x; 1.6812x over previous
//
#include <hip/hip_runtime.h>

// Problem constants (B=4, L=4096, E=512, H=16, D=32)
#define EMBED  512
#define NHEAD  16
#define HDIM   32
#define NBATCH 4
#define SEQ    4096
#define NROWS  (NBATCH * SEQ)   // 16384
#define FEPS   1e-6f

typedef __attribute__((ext_vector_type(8))) short short8;
typedef __attribute__((ext_vector_type(4))) float f32x4;

// ---- bf16 split helpers (RNE) ----
__device__ __forceinline__ short f2bf(float x) {
    unsigned u = __float_as_uint(x);
    u += 0x7FFFu + ((u >> 16) & 1u);
    return (short)(u >> 16);
}
__device__ __forceinline__ float bf2f(short h) {
    return __uint_as_float(((unsigned)(unsigned short)h) << 16);
}

// ---- weight split: W fp32 -> Whi/Wlo bf16 (same row-major layout) ----
__global__ __launch_bounds__(256)
void convert_w(const float* __restrict__ W, short* __restrict__ hi,
               short* __restrict__ lo) {
    int i = (blockIdx.x * 256 + threadIdx.x) * 4;
    float4 v = *(const float4*)(W + i);
    short4 h, l;
    h.x = f2bf(v.x); l.x = f2bf(v.x - bf2f(h.x));
    h.y = f2bf(v.y); l.y = f2bf(v.y - bf2f(h.y));
    h.z = f2bf(v.z); l.z = f2bf(v.z - bf2f(h.z));
    h.w = f2bf(v.w); l.w = f2bf(v.w - bf2f(h.w));
    *(short4*)(hi + i) = h;
    *(short4*)(lo + i) = l;
}

// ---- split-bf16 MFMA GEMM: C[m,n] = sum_k A[m,k] * W[n,k] ----
// A: fp32 NROWS x EMBED. W pre-split hi/lo bf16, row-major N x K.
// 128x128 tile, 256 threads (4 waves in 2x2), 16x16x32 bf16 MFMA, 3-term split.
// EPI: 0=none, 1=elu(x)+1, 2=x/SEQ
#define LDA 40   // padded LDS row (shorts): 80B stride -> 2-way conflicts only

template <int EPI>
__global__ __launch_bounds__(256, 2)
void gemm_mfma(const float* __restrict__ A, const short* __restrict__ Whi,
               const short* __restrict__ Wlo, float* __restrict__ C) {
    __shared__ short Ah[128][LDA];
    __shared__ short Al[128][LDA];

    const int tid  = threadIdx.x;
    const int lane = tid & 63;
    const int wave = tid >> 6;
    const int wm   = (wave >> 1) * 64;   // wave's m-offset in tile
    const int wn   = (wave & 1) * 64;    // wave's n-offset in tile
    const int l15  = lane & 15;
    const int kg   = lane >> 4;          // quad 0..3
    const int bm   = blockIdx.y * 128;
    const int bn   = blockIdx.x * 128;

    // staging: thread loads A rows sr and sr+64, k-offset sk (8 fp32 each)
    const int sr = tid >> 2;
    const int sk = (tid & 3) * 8;
    const float* Ap0 = A + (size_t)(bm + sr) * EMBED + sk;
    const float* Ap1 = Ap0 + (size_t)64 * EMBED;

    // B fragments straight from global (L2-resident 1MB): lane l needs
    // W[bn+wn+j*16+l15][k0 + kg*8 .. +7]
    const short* Bh = Whi + (size_t)(bn + wn + l15) * EMBED + kg * 8;
    const short* Bl = Wlo + (size_t)(bn + wn + l15) * EMBED + kg * 8;

    f32x4 acc[4][4];
#pragma unroll
    for (int i = 0; i < 4; ++i)
#pragma unroll
        for (int j = 0; j < 4; ++j) acc[i][j] = (f32x4)0.0f;

#pragma unroll 1
    for (int k0 = 0; k0 < EMBED; k0 += 32) {
        float4 a0 = *(const float4*)(Ap0 + k0);
        float4 a1 = *(const float4*)(Ap0 + k0 + 4);
        float4 a2 = *(const float4*)(Ap1 + k0);
        float4 a3 = *(const float4*)(Ap1 + k0 + 4);
        short8 bh[4], bl[4];
#pragma unroll
        for (int j = 0; j < 4; ++j) {
            bh[j] = *(const short8*)(Bh + (size_t)j * 16 * EMBED + k0);
            bl[j] = *(const short8*)(Bl + (size_t)j * 16 * EMBED + k0);
        }
        __syncthreads();   // protect previous iteration's LDS reads
        {
            float v[8] = {a0.x, a0.y, a0.z, a0.w, a1.x, a1.y, a1.z, a1.w};
            short8 hv, lv;
#pragma unroll
            for (int i = 0; i < 8; ++i) {
                short hb = f2bf(v[i]);
                hv[i] = hb; lv[i] = f2bf(v[i] - bf2f(hb));
            }
            *(short8*)&Ah[sr][sk] = hv;
            *(short8*)&Al[sr][sk] = lv;
        }
        {
            float v[8] = {a2.x, a2.y, a2.z, a2.w, a3.x, a3.y, a3.z, a3.w};
            short8 hv, lv;
#pragma unroll
            for (int i = 0; i < 8; ++i) {
                short hb = f2bf(v[i]);
                hv[i] = hb; lv[i] = f2bf(v[i] - bf2f(hb));
            }
            *(short8*)&Ah[sr + 64][sk] = hv;
            *(short8*)&Al[sr + 64][sk] = lv;
        }
        __syncthreads();

        short8 ah[4], al[4];
#pragma unroll
        for (int i = 0; i < 4; ++i) {
            ah[i] = *(const short8*)&Ah[wm + i * 16 + l15][kg * 8];
            al[i] = *(const short8*)&Al[wm + i * 16 + l15][kg * 8];
        }
#pragma unroll
        for (int i = 0; i < 4; ++i)
#pragma unroll
            for (int j = 0; j < 4; ++j) {
                acc[i][j] = __builtin_amdgcn_mfma_f32_16x16x32_bf16(ah[i], bh[j], acc[i][j], 0, 0, 0);
                acc[i][j] = __builtin_amdgcn_mfma_f32_16x16x32_bf16(ah[i], bl[j], acc[i][j], 0, 0, 0);
                acc[i][j] = __builtin_amdgcn_mfma_f32_16x16x32_bf16(al[i], bh[j], acc[i][j], 0, 0, 0);
            }
    }

    // epilogue: C/D layout col=lane&15, row=(lane>>4)*4+r
#pragma unroll
    for (int i = 0; i < 4; ++i)
#pragma unroll
        for (int j = 0; j < 4; ++j) {
            const int col = bn + wn + j * 16 + l15;
#pragma unroll
            for (int r = 0; r < 4; ++r) {
                const int row = bm + wm + i * 16 + kg * 4 + r;
                float vv = acc[i][j][r];
                if (EPI == 1) vv = (vv > 0.f) ? (vv + 1.f) : __expf(vv);
                else if (EPI == 2) vv = vv * (1.0f / (float)SEQ);
                C[(size_t)row * EMBED + col] = vv;
            }
        }
}

// ---- KV[b,h,d,e] = sum_s K[b,s,h,d]*V[b,s,h,e]; Ksum[b,h,d] = sum_s K ----
// grid (8 s-chunks, 64 bh), 256 threads; 32x32 LDS tiles; fp32 atomics.
__global__ __launch_bounds__(256)
void kv_ksum_kernel(const float* __restrict__ Kf, const float* __restrict__ Vf,
                    float* __restrict__ KV, float* __restrict__ Ksum) {
    const int bh = blockIdx.y;
    const int b  = bh >> 4;
    const int h  = bh & 15;
    const int s0 = blockIdx.x * (SEQ / 8);
    const int t  = threadIdx.x;
    const int e  = t & 31;
    const int dg = t >> 5;            // 0..7 -> d = dg*4 + i

    __shared__ float Ks[32][32];
    __shared__ float Vs[32][32];
    const int lr = t >> 3, lc = (t & 7) * 4;

    const float* Kbase = Kf + (size_t)b * SEQ * EMBED + h * HDIM;
    const float* Vbase = Vf + (size_t)b * SEQ * EMBED + h * HDIM;

    float a0 = 0.f, a1 = 0.f, a2 = 0.f, a3 = 0.f, ks = 0.f;
    for (int s = s0; s < s0 + SEQ / 8; s += 32) {
        float4 kx = *(const float4*)(Kbase + (size_t)(s + lr) * EMBED + lc);
        float4 vx = *(const float4*)(Vbase + (size_t)(s + lr) * EMBED + lc);
        __syncthreads();
        *(float4*)&Ks[lr][lc] = kx;
        *(float4*)&Vs[lr][lc] = vx;
        __syncthreads();
#pragma unroll
        for (int rr = 0; rr < 32; ++rr) {
            float v = Vs[rr][e];
            a0 = fmaf(Ks[rr][dg * 4 + 0], v, a0);
            a1 = fmaf(Ks[rr][dg * 4 + 1], v, a1);
            a2 = fmaf(Ks[rr][dg * 4 + 2], v, a2);
            a3 = fmaf(Ks[rr][dg * 4 + 3], v, a3);
            if (dg == 0) ks += Ks[rr][e];
        }
    }
    float* kvp = KV + ((size_t)bh * HDIM + dg * 4) * HDIM + e;
    atomicAdd(kvp + 0 * HDIM, a0);
    atomicAdd(kvp + 1 * HDIM, a1);
    atomicAdd(kvp + 2 * HDIM, a2);
    atomicAdd(kvp + 3 * HDIM, a3);
    if (dg == 0) atomicAdd(&Ksum[bh * HDIM + e], ks);
}

// ---- message (in place): Q[l,h,:] <- (SEQ/(Q.Ksum+eps)) * Q @ KV[b,h] ----
// 4 rows per block, KV column held in 32 registers (L2-hit loads).
__global__ __launch_bounds__(512)
void message_kernel(float* __restrict__ Q, const float* __restrict__ KV,
                    const float* __restrict__ Ksum) {
    const int blk  = blockIdx.x;        // 0..4095
    const int row0 = blk * 4;
    const int b    = row0 >> 12;
    const int t    = threadIdx.x;
    const int h    = t >> 5, e = t & 31;

    __shared__ float q[4][EMBED];
    __shared__ float ks[EMBED];
    ks[t] = Ksum[b * EMBED + t];
#pragma unroll
    for (int r = 0; r < 4; ++r) q[r][t] = Q[(size_t)(row0 + r) * EMBED + t];

    const float* kvh = KV + (size_t)(b * NHEAD + h) * HDIM * HDIM + e;
    float kc[HDIM];
#pragma unroll
    for (int d = 0; d < HDIM; ++d) kc[d] = kvh[d * HDIM];
    __syncthreads();

#pragma unroll
    for (int r = 0; r < 4; ++r) {
        float zden = FEPS, m = 0.f;
#pragma unroll
        for (int d = 0; d < HDIM; ++d) {
            float qd = q[r][h * HDIM + d];
            zden = fmaf(qd, ks[h * HDIM + d], zden);
            m    = fmaf(qd, kc[d], m);
        }
        Q[(size_t)(row0 + r) * EMBED + t] = m * ((float)SEQ / zden);
    }
}

// ---- launch ----
extern "C" void kernel_launch(void* const* d_in, const int* in_sizes, int n_in,
                              void* d_out, int out_size, void* d_ws, size_t ws_size,
                              hipStream_t stream) {
    const float* query = (const float*)d_in[0];
    const float* key   = (const float*)d_in[1];
    const float* value = (const float*)d_in[2];
    const float* Wq    = (const float*)d_in[3];
    const float* Wk    = (const float*)d_in[4];
    const float* Wv    = (const float*)d_in[5];
    const float* Wm    = (const float*)d_in[6];
    float* out = (float*)d_out;

    float* ws  = (float*)d_ws;
    float* Qb  = ws;                              // 16384*512 fp32
    float* Kb  = Qb + (size_t)NROWS * EMBED;
    float* Vb  = Kb + (size_t)NROWS * EMBED;
    float* KVb = Vb + (size_t)NROWS * EMBED;      // 64*32*32
    float* KSb = KVb + 64 * HDIM * HDIM;          // 64*32
    short* wsp = (short*)(KSb + 64 * HDIM);       // split weights: 8 x 512KB
    const int WN = EMBED * EMBED;                 // 262144
    short* WqH = wsp;            short* WqL = wsp + WN;
    short* WkH = wsp + 2 * WN;   short* WkL = wsp + 3 * WN;
    short* WvH = wsp + 4 * WN;   short* WvL = wsp + 5 * WN;
    short* WmH = wsp + 6 * WN;   short* WmL = wsp + 7 * WN;

    hipMemsetAsync(KVb, 0, (64 * HDIM * HDIM + 64 * HDIM) * sizeof(float), stream);

    const int cblk = WN / (256 * 4);              // 256 blocks
    convert_w<<<cblk, 256, 0, stream>>>(Wq, WqH, WqL);
    convert_w<<<cblk, 256, 0, stream>>>(Wk, WkH, WkL);
    convert_w<<<cblk, 256, 0, stream>>>(Wv, WvH, WvL);
    convert_w<<<cblk, 256, 0, stream>>>(Wm, WmH, WmL);

    dim3 g(EMBED / 128, NROWS / 128);             // (4,128) = 512 blocks
    gemm_mfma<1><<<g, 256, 0, stream>>>(query, WqH, WqL, Qb);
    gemm_mfma<1><<<g, 256, 0, stream>>>(key,   WkH, WkL, Kb);
    gemm_mfma<2><<<g, 256, 0, stream>>>(value, WvH, WvL, Vb);

    kv_ksum_kernel<<<dim3(8, 64), 256, 0, stream>>>(Kb, Vb, KVb, KSb);
    message_kernel<<<NROWS / 4, 512, 0, stream>>>(Qb, KVb, KSb);

    gemm_mfma<0><<<g, 256, 0, stream>>>(Qb, WmH, WmL, out);
}